// Round 2
// baseline (3227.275 us; speedup 1.0000x reference)
//
#include <hip/hip_runtime.h>

// ---------------------------------------------------------------------------
// TypeNet: 3 branches x (BN1 -> flattened LSTM (2048 steps) -> BN2 -> LSTM (2048 steps))
// H = 128, gates = 512. Recurrence via mfma_f32_16x16x32_f16 (f32 accum).
// Round 2: single lgkm-only barrier per step (raw s_barrier, no vmcnt drain);
// gate-permuted row ownership so gate->epilogue exchange is in-wave.
// ---------------------------------------------------------------------------

typedef _Float16 half8 __attribute__((ext_vector_type(8)));
typedef float float4_t __attribute__((ext_vector_type(4)));

__device__ __forceinline__ float sigm(float x) { return 1.0f / (1.0f + __expf(-x)); }
__device__ __forceinline__ float tanh_fast(float x) { return 1.0f - 2.0f / (__expf(2.0f * x) + 1.0f); }

// Barrier with LDS-visibility only: does NOT drain vmcnt, so global stores /
// prefetch loads stay in flight across it. All cross-wave deps here are LDS.
__device__ __forceinline__ void lds_barrier() {
  asm volatile("s_waitcnt lgkmcnt(0)\n\ts_barrier" ::: "memory");
}
// In-wave LDS write->read ordering.
__device__ __forceinline__ void lds_wave_fence() {
  asm volatile("s_waitcnt lgkmcnt(0)" ::: "memory");
}

// ---------------------------------------------------------------------------
// K1: BN1 over branch slice [128,16,3]; writes xbn[br][s=t*128+b][d].
// ---------------------------------------------------------------------------
__global__ __launch_bounds__(128) void bn1_kernel(const float* __restrict__ x,
                                                  const float* __restrict__ g1,
                                                  const float* __restrict__ b1,
                                                  float* __restrict__ xbn) {
  const int br = blockIdx.x >> 4;
  const int t  = blockIdx.x & 15;
  const int b  = threadIdx.x;
  const float* px = x + (b * 48 + br * 16 + t) * 3;
  const float v0 = px[0], v1 = px[1], v2 = px[2];
  float s  = v0 + v1 + v2;
  float ss = v0 * v0 + v1 * v1 + v2 * v2;
  for (int off = 32; off; off >>= 1) {
    s  += __shfl_down(s, off);
    ss += __shfl_down(ss, off);
  }
  __shared__ float red[4];
  if ((threadIdx.x & 63) == 0) {
    red[(threadIdx.x >> 6) * 2]     = s;
    red[(threadIdx.x >> 6) * 2 + 1] = ss;
  }
  __syncthreads();
  const float S = red[0] + red[2], SS = red[1] + red[3];
  const float mean = S * (1.0f / 384.0f);
  const float var  = SS * (1.0f / 384.0f) - mean * mean;
  const float rstd = rsqrtf(var + 1e-5f);
  const float a  = g1[t] * rstd;
  const float sh = b1[t] - mean * a;
  float* dst = xbn + br * 6144 + (t * 128 + b) * 3;
  dst[0] = v0 * a + sh;
  dst[1] = v1 * a + sh;
  dst[2] = v2 * a + sh;
}

// ---------------------------------------------------------------------------
// K3a: BN2 stats per (branch, channel) over 2048 elems of H1.
// ---------------------------------------------------------------------------
__global__ __launch_bounds__(256) void bn2stats_kernel(const float* __restrict__ H1,
                                                       float* __restrict__ stats) {
  const int br = blockIdx.x >> 7;
  const int ch = blockIdx.x & 127;
  const float* base = H1 + (size_t)br * 262144 + ch * 128;
  float s = 0.f, ss = 0.f;
  for (int k = threadIdx.x; k < 2048; k += 256) {
    const int t1 = k >> 7, h = k & 127;
    const float v = base[t1 * 16384 + h];
    s += v;
    ss += v * v;
  }
  for (int off = 32; off; off >>= 1) {
    s  += __shfl_down(s, off);
    ss += __shfl_down(ss, off);
  }
  __shared__ float red[8];
  if ((threadIdx.x & 63) == 0) {
    red[(threadIdx.x >> 6) * 2]     = s;
    red[(threadIdx.x >> 6) * 2 + 1] = ss;
  }
  __syncthreads();
  if (threadIdx.x == 0) {
    const float S  = red[0] + red[2] + red[4] + red[6];
    const float SS = red[1] + red[3] + red[5] + red[7];
    const float mean = S * (1.0f / 2048.0f);
    const float var  = SS * (1.0f / 2048.0f) - mean * mean;
    stats[(br * 128 + ch) * 2]     = mean;
    stats[(br * 128 + ch) * 2 + 1] = rsqrtf(var + 1e-5f);
  }
}

// ---------------------------------------------------------------------------
// K3b: G2x[br][s2][g] = Wih2 @ BN2(H1) + bih2 + bhh2, one block per (br, t2).
// ---------------------------------------------------------------------------
__global__ __launch_bounds__(256) void g2x_kernel(
    const float* __restrict__ H1, const float* __restrict__ stats,
    const float* __restrict__ g2, const float* __restrict__ b2v,
    const float* __restrict__ Wih2, const float* __restrict__ bih2,
    const float* __restrict__ bhh2, float* __restrict__ G2x) {
  const int br = blockIdx.x >> 7;
  const int t2 = blockIdx.x & 127;
  __shared__ float xh[2048];
  __shared__ float wt[64 * 129];
  const float mean = stats[(br * 128 + t2) * 2];
  const float rstd = stats[(br * 128 + t2) * 2 + 1];
  const float a  = g2[t2] * rstd;
  const float sh = b2v[t2] - mean * a;
  for (int e = threadIdx.x; e < 2048; e += 256) {
    const int b2 = e >> 7, d = e & 127;
    xh[e] = H1[(size_t)br * 262144 + (size_t)(b2 * 128 + t2) * 128 + d] * a + sh;
  }
  const int gl  = threadIdx.x & 63;
  const int b2b = (threadIdx.x >> 6) * 4;
  for (int gt = 0; gt < 8; ++gt) {
    __syncthreads();
    for (int e = threadIdx.x; e < 8192; e += 256)
      wt[(e >> 7) * 129 + (e & 127)] = Wih2[gt * 8192 + e];
    __syncthreads();
    float a0 = 0.f, a1 = 0.f, a2 = 0.f, a3 = 0.f;
    for (int d = 0; d < 128; ++d) {
      const float w = wt[gl * 129 + d];
      a0 += w * xh[(b2b + 0) * 128 + d];
      a1 += w * xh[(b2b + 1) * 128 + d];
      a2 += w * xh[(b2b + 2) * 128 + d];
      a3 += w * xh[(b2b + 3) * 128 + d];
    }
    const int g   = gt * 64 + gl;
    const float bb = bih2[g] + bhh2[g];
    float* dst = G2x + ((size_t)br * 2048 + t2 * 16) * 512 + g;
    dst[(b2b + 0) * 512] = a0 + bb;
    dst[(b2b + 1) * 512] = a1 + bb;
    dst[(b2b + 2) * 512] = a2 + bb;
    dst[(b2b + 3) * 512] = a3 + bb;
  }
}

// ---------------------------------------------------------------------------
// K2/K4: the recurrence. 1 block/branch, 4 waves. Wave w owns Whh rows
// {gate*128 + w*32 + j : gate in 0..3, j in 0..31} (gate-permuted), so the
// epilogue for h-indices [32w, 32w+32) is entirely in-wave. m-tile mt:
// gate = mt>>1, rows j = w*32 + (mt&1)*16 + l15. A-frag layout:
// A[m=lane&15][k=quad*8+j]; D: col=lane&15 (all cols equal), row=quad*4+reg.
// One lgkm-only barrier per step (h broadcast); h_sh double-buffered.
// ---------------------------------------------------------------------------
template <int LAYER>
__global__ __launch_bounds__(256, 1) void lstm_kernel(
    const float* __restrict__ Whh, const float* __restrict__ Wih,
    const float* __restrict__ bih, const float* __restrict__ bhh,
    const float* __restrict__ h0s, const float* __restrict__ c0s,
    const float* __restrict__ xbn, const float* __restrict__ G2x,
    float* __restrict__ H1, float* __restrict__ outp) {
  const int br   = blockIdx.x;
  const int tid  = threadIdx.x;
  const int wave = tid >> 6;
  const int lane = tid & 63;
  const int quad = lane >> 4;
  const int l15  = lane & 15;

  __shared__ __align__(16) _Float16 h_sh[2][128];  // double-buffered h state
  __shared__ __align__(16) float gws[512];          // per-wave gate regions
  __shared__ float xs[(LAYER == 1) ? 6144 : 64];

  // ---- preload Whh as f16 A-fragments (gate-permuted rows) ----
  half8 afrag[8][4];
#pragma unroll
  for (int mt = 0; mt < 8; ++mt) {
    const int gate = mt >> 1;
    const int row  = gate * 128 + wave * 32 + (mt & 1) * 16 + l15;
#pragma unroll
    for (int kt = 0; kt < 4; ++kt) {
      const float* src = Whh + row * 128 + kt * 32 + quad * 8;
      half8 f;
#pragma unroll
      for (int jj = 0; jj < 8; ++jj) f[jj] = (_Float16)src[jj];
      afrag[mt][kt] = f;
    }
  }

  if (LAYER == 1) {
    for (int i = tid; i < 6144; i += 256) xs[i] = xbn[br * 6144 + i];
  }

  const int s0   = 2 * br + (LAYER - 1);
  const int hidx = wave * 32 + lane;  // valid for lane < 32
  float c = 0.f;
  float bi = 0.f, bf = 0.f, bg = 0.f, bo = 0.f;
  float wxi[3] = {0, 0, 0}, wxf[3] = {0, 0, 0}, wxg[3] = {0, 0, 0}, wxo[3] = {0, 0, 0};
  if (lane < 32) {
    c = c0s[s0 * 128 + hidx];
    if (LAYER == 1) {
      bi = bih[hidx] + bhh[hidx];
      bf = bih[128 + hidx] + bhh[128 + hidx];
      bg = bih[256 + hidx] + bhh[256 + hidx];
      bo = bih[384 + hidx] + bhh[384 + hidx];
#pragma unroll
      for (int d = 0; d < 3; ++d) {
        wxi[d] = Wih[hidx * 3 + d];
        wxf[d] = Wih[(128 + hidx) * 3 + d];
        wxg[d] = Wih[(256 + hidx) * 3 + d];
        wxo[d] = Wih[(384 + hidx) * 3 + d];
      }
    }
  }
  if (tid < 128) h_sh[0][tid] = (_Float16)h0s[s0 * 128 + tid];

  // LAYER 2: depth-2 register prefetch of G2x gate rows (bias folded in).
  const float* gbase =
      (LAYER == 2) ? (G2x + (size_t)br * 2048 * 512 + hidx) : (const float*)nullptr;
  float c0g = 0.f, c1g = 0.f, c2g = 0.f, c3g = 0.f;
  float n0g = 0.f, n1g = 0.f, n2g = 0.f, n3g = 0.f;
  if (LAYER == 2 && lane < 32) {
    c0g = gbase[0];   c1g = gbase[128]; c2g = gbase[256]; c3g = gbase[384];
    n0g = gbase[512]; n1g = gbase[640]; n2g = gbase[768]; n3g = gbase[896];
  }

  __syncthreads();  // once; full drain is fine here

#pragma unroll 2
  for (int s = 0; s < 2048; ++s) {
    // prefetch step s+2 (hidden under MFMA + epilogue; no barrier drains it)
    float p0 = 0.f, p1 = 0.f, p2 = 0.f, p3 = 0.f;
    if (LAYER == 2) {
      if (lane < 32 && s + 2 < 2048) {
        const float* gp = gbase + (size_t)(s + 2) * 512;
        p0 = gp[0]; p1 = gp[128]; p2 = gp[256]; p3 = gp[384];
      }
    }

    // B fragments: every lane supplies h[k] -> every D column is the matvec
    const _Float16* hcur = h_sh[s & 1];
    half8 bfrag[4];
#pragma unroll
    for (int kt = 0; kt < 4; ++kt)
      bfrag[kt] = *reinterpret_cast<const half8*>(&hcur[kt * 32 + quad * 8]);

#pragma unroll
    for (int mt = 0; mt < 8; ++mt) {
      float4_t acc = {0.f, 0.f, 0.f, 0.f};
#pragma unroll
      for (int kt = 0; kt < 4; ++kt)
        acc = __builtin_amdgcn_mfma_f32_16x16x32_f16(afrag[mt][kt], bfrag[kt], acc, 0, 0, 0);
      if (l15 == 0) {
        // wave-private region: gws[wave*128 + gate*32 + (mt&1)*16 + quad*4 ..]
        *reinterpret_cast<float4_t*>(
            &gws[wave * 128 + (mt >> 1) * 32 + (mt & 1) * 16 + quad * 4]) = acc;
      }
    }
    lds_wave_fence();  // in-wave gate write -> read ordering (no barrier)

    if (lane < 32) {
      float gi = gws[wave * 128 + lane];
      float gf = gws[wave * 128 + 32 + lane];
      float gg = gws[wave * 128 + 64 + lane];
      float go = gws[wave * 128 + 96 + lane];
      if (LAYER == 1) {
        const float x0 = xs[s * 3], x1 = xs[s * 3 + 1], x2 = xs[s * 3 + 2];
        gi += bi + wxi[0] * x0 + wxi[1] * x1 + wxi[2] * x2;
        gf += bf + wxf[0] * x0 + wxf[1] * x1 + wxf[2] * x2;
        gg += bg + wxg[0] * x0 + wxg[1] * x1 + wxg[2] * x2;
        go += bo + wxo[0] * x0 + wxg[2] * 0.f + wxo[0] * 0.f + wxo[0] * x0 * 0.f + wxo[1] * x1 * 0.f + wxo[2] * x2 * 0.f + wxo[0] * x0 + wxo[1] * x1 + wxo[2] * x2 - wxo[0] * x0;
      } else {
        gi += c0g; gf += c1g; gg += c2g; go += c3g;
      }
      const float iv = sigm(gi);
      const float fv = sigm(gf);
      const float gv = tanh_fast(gg);
      const float ov = sigm(go);
      c = fv * c + iv * gv;
      const float hv = ov * tanh_fast(c);
      h_sh[(s + 1) & 1][hidx] = (_Float16)hv;
      if (LAYER == 1)
        H1[((size_t)br * 2048 + (size_t)s) * 128 + hidx] = hv;
      else
        outp[(size_t)br * 262144 + (size_t)s * 128 + hidx] = hv;
    }
    if (LAYER == 2) {
      c0g = n0g; c1g = n1g; c2g = n2g; c3g = n3g;
      n0g = p0;  n1g = p1;  n2g = p2;  n3g = p3;
    }
    lds_barrier();  // h broadcast; lgkm-only, stores stay in flight
  }
}

// ---------------------------------------------------------------------------
// Workspace layout (floats): xbn@0 (18432) | H1@18432 (786432) |
// stats@804864 (768) | G2x@805632 (3145728)
// ---------------------------------------------------------------------------
extern "C" void kernel_launch(void* const* d_in, const int* in_sizes, int n_in,
                              void* d_out, int out_size, void* d_ws, size_t ws_size,
                              hipStream_t stream) {
  const float* x    = (const float*)d_in[0];
  const float* g1   = (const float*)d_in[1];
  const float* b1   = (const float*)d_in[2];
  const float* Wih1 = (const float*)d_in[3];
  const float* Whh1 = (const float*)d_in[4];
  const float* bih1 = (const float*)d_in[5];
  const float* bhh1 = (const float*)d_in[6];
  const float* g2   = (const float*)d_in[7];
  const float* b2   = (const float*)d_in[8];
  const float* Wih2 = (const float*)d_in[9];
  const float* Whh2 = (const float*)d_in[10];
  const float* bih2 = (const float*)d_in[11];
  const float* bhh2 = (const float*)d_in[12];
  const float* h0s  = (const float*)d_in[13];
  const float* c0s  = (const float*)d_in[14];

  float* ws   = (float*)d_ws;
  float* xbn  = ws;
  float* H1b  = ws + 18432;
  float* st   = ws + 18432 + 786432;
  float* G2xb = st + 768;
  float* outp = (float*)d_out;

  bn1_kernel<<<48, 128, 0, stream>>>(x, g1, b1, xbn);
  lstm_kernel<1><<<3, 256, 0, stream>>>(Whh1, Wih1, bih1, bhh1, h0s, c0s, xbn,
                                        nullptr, H1b, nullptr);
  bn2stats_kernel<<<384, 256, 0, stream>>>(H1b, st);
  g2x_kernel<<<384, 256, 0, stream>>>(H1b, st, g2, b2, Wih2, bih2, bhh2, G2xb);
  lstm_kernel<2><<<3, 256, 0, stream>>>(Whh2, nullptr, bih2, bhh2, h0s, c0s,
                                        nullptr, G2xb, nullptr, outp);
}

// Round 3
// 2290.427 us; speedup vs baseline: 1.4090x; 1.4090x over previous
//
#include <hip/hip_runtime.h>

// ---------------------------------------------------------------------------
// TypeNet: 3 branches x (BN1 -> flattened LSTM (2048 steps) -> BN2 -> LSTM (2048 steps))
// H = 128, gates = 512. Recurrence via mfma_f32_16x16x32_f16 (f32 accum).
// Round 3: epilogue reads gates straight from acc registers (v_cndmask
// selects; all 16 D-columns are identical so every lane in quad q holds rows
// q*4..q*4+3 of every tile). Fast exp2/rcp transcendentals. One lgkm-only
// barrier per step (the h broadcast) is the only LDS round-trip left.
// ---------------------------------------------------------------------------

typedef _Float16 half8 __attribute__((ext_vector_type(8)));
typedef float float4_t __attribute__((ext_vector_type(4)));

__device__ __forceinline__ float fast_exp(float x) {
  return __builtin_amdgcn_exp2f(x * 1.44269504f);
}
__device__ __forceinline__ float fast_rcp(float x) { return __builtin_amdgcn_rcpf(x); }
__device__ __forceinline__ float sigm(float x) { return fast_rcp(1.0f + fast_exp(-x)); }
// correct limits: x>>0 -> exp inf -> rcp 0 -> 1; x<<0 -> exp 0 -> -1.
__device__ __forceinline__ float tanh_fast(float x) {
  return 1.0f - 2.0f * fast_rcp(1.0f + fast_exp(2.0f * x));
}

// Barrier with LDS-visibility only: does NOT drain vmcnt, so global stores /
// prefetch loads stay in flight across it. All cross-wave deps here are LDS.
__device__ __forceinline__ void lds_barrier() {
  asm volatile("s_waitcnt lgkmcnt(0)\n\ts_barrier" ::: "memory");
}

// select acc[rr] (rr in 0..3) then pick lo/hi tile by hh — pure v_cndmask.
__device__ __forceinline__ float gsel(float4_t lo, float4_t hi, bool r1, bool r2, bool bh) {
  const float a  = r1 ? lo[1] : lo[0];
  const float b  = r1 ? lo[3] : lo[2];
  const float x  = r2 ? b : a;
  const float a2 = r1 ? hi[1] : hi[0];
  const float b2 = r1 ? hi[3] : hi[2];
  const float y  = r2 ? b2 : a2;
  return bh ? y : x;
}

// ---------------------------------------------------------------------------
// K1: BN1 over branch slice [128,16,3]; writes xbn[br][s=t*128+b][d].
// ---------------------------------------------------------------------------
__global__ __launch_bounds__(128) void bn1_kernel(const float* __restrict__ x,
                                                  const float* __restrict__ g1,
                                                  const float* __restrict__ b1,
                                                  float* __restrict__ xbn) {
  const int br = blockIdx.x >> 4;
  const int t  = blockIdx.x & 15;
  const int b  = threadIdx.x;
  const float* px = x + (b * 48 + br * 16 + t) * 3;
  const float v0 = px[0], v1 = px[1], v2 = px[2];
  float s  = v0 + v1 + v2;
  float ss = v0 * v0 + v1 * v1 + v2 * v2;
  for (int off = 32; off; off >>= 1) {
    s  += __shfl_down(s, off);
    ss += __shfl_down(ss, off);
  }
  __shared__ float red[4];
  if ((threadIdx.x & 63) == 0) {
    red[(threadIdx.x >> 6) * 2]     = s;
    red[(threadIdx.x >> 6) * 2 + 1] = ss;
  }
  __syncthreads();
  const float S = red[0] + red[2], SS = red[1] + red[3];
  const float mean = S * (1.0f / 384.0f);
  const float var  = SS * (1.0f / 384.0f) - mean * mean;
  const float rstd = rsqrtf(var + 1e-5f);
  const float a  = g1[t] * rstd;
  const float sh = b1[t] - mean * a;
  float* dst = xbn + br * 6144 + (t * 128 + b) * 3;
  dst[0] = v0 * a + sh;
  dst[1] = v1 * a + sh;
  dst[2] = v2 * a + sh;
}

// ---------------------------------------------------------------------------
// K3a: BN2 stats per (branch, channel) over 2048 elems of H1.
// ---------------------------------------------------------------------------
__global__ __launch_bounds__(256) void bn2stats_kernel(const float* __restrict__ H1,
                                                       float* __restrict__ stats) {
  const int br = blockIdx.x >> 7;
  const int ch = blockIdx.x & 127;
  const float* base = H1 + (size_t)br * 262144 + ch * 128;
  float s = 0.f, ss = 0.f;
  for (int k = threadIdx.x; k < 2048; k += 256) {
    const int t1 = k >> 7, h = k & 127;
    const float v = base[t1 * 16384 + h];
    s += v;
    ss += v * v;
  }
  for (int off = 32; off; off >>= 1) {
    s  += __shfl_down(s, off);
    ss += __shfl_down(ss, off);
  }
  __shared__ float red[8];
  if ((threadIdx.x & 63) == 0) {
    red[(threadIdx.x >> 6) * 2]     = s;
    red[(threadIdx.x >> 6) * 2 + 1] = ss;
  }
  __syncthreads();
  if (threadIdx.x == 0) {
    const float S  = red[0] + red[2] + red[4] + red[6];
    const float SS = red[1] + red[3] + red[5] + red[7];
    const float mean = S * (1.0f / 2048.0f);
    const float var  = SS * (1.0f / 2048.0f) - mean * mean;
    stats[(br * 128 + ch) * 2]     = mean;
    stats[(br * 128 + ch) * 2 + 1] = rsqrtf(var + 1e-5f);
  }
}

// ---------------------------------------------------------------------------
// K3b: G2x[br][s2][g] = Wih2 @ BN2(H1) + bih2 + bhh2, one block per (br, t2).
// ---------------------------------------------------------------------------
__global__ __launch_bounds__(256) void g2x_kernel(
    const float* __restrict__ H1, const float* __restrict__ stats,
    const float* __restrict__ g2, const float* __restrict__ b2v,
    const float* __restrict__ Wih2, const float* __restrict__ bih2,
    const float* __restrict__ bhh2, float* __restrict__ G2x) {
  const int br = blockIdx.x >> 7;
  const int t2 = blockIdx.x & 127;
  __shared__ float xh[2048];
  __shared__ float wt[64 * 129];
  const float mean = stats[(br * 128 + t2) * 2];
  const float rstd = stats[(br * 128 + t2) * 2 + 1];
  const float a  = g2[t2] * rstd;
  const float sh = b2v[t2] - mean * a;
  for (int e = threadIdx.x; e < 2048; e += 256) {
    const int b2 = e >> 7, d = e & 127;
    xh[e] = H1[(size_t)br * 262144 + (size_t)(b2 * 128 + t2) * 128 + d] * a + sh;
  }
  const int gl  = threadIdx.x & 63;
  const int b2b = (threadIdx.x >> 6) * 4;
  for (int gt = 0; gt < 8; ++gt) {
    __syncthreads();
    for (int e = threadIdx.x; e < 8192; e += 256)
      wt[(e >> 7) * 129 + (e & 127)] = Wih2[gt * 8192 + e];
    __syncthreads();
    float a0 = 0.f, a1 = 0.f, a2 = 0.f, a3 = 0.f;
    for (int d = 0; d < 128; ++d) {
      const float w = wt[gl * 129 + d];
      a0 += w * xh[(b2b + 0) * 128 + d];
      a1 += w * xh[(b2b + 1) * 128 + d];
      a2 += w * xh[(b2b + 2) * 128 + d];
      a3 += w * xh[(b2b + 3) * 128 + d];
    }
    const int g   = gt * 64 + gl;
    const float bb = bih2[g] + bhh2[g];
    float* dst = G2x + ((size_t)br * 2048 + t2 * 16) * 512 + g;
    dst[(b2b + 0) * 512] = a0 + bb;
    dst[(b2b + 1) * 512] = a1 + bb;
    dst[(b2b + 2) * 512] = a2 + bb;
    dst[(b2b + 3) * 512] = a3 + bb;
  }
}

// ---------------------------------------------------------------------------
// K2/K4: the recurrence. 1 block/branch, 4 waves. Wave w owns Whh rows
// {gate*128 + w*32 + half*16 + m : gate 0..3, half 0..1, m 0..15} as
// A-fragments (mt = gate*2 + half). D rows quad*4..quad*4+3 live in the 4 acc
// regs of EVERY lane in that quad (all 16 cols equal). Epilogue lane mapping:
// j = wave*32 + (l15>>3)*16 + quad*4 + (l15&3); gate values via cndmask
// selects from acc — no LDS gate exchange. One lgkm-only barrier per step.
// ---------------------------------------------------------------------------
template <int LAYER>
__global__ __launch_bounds__(256, 1) void lstm_kernel(
    const float* __restrict__ Whh, const float* __restrict__ Wih,
    const float* __restrict__ bih, const float* __restrict__ bhh,
    const float* __restrict__ h0s, const float* __restrict__ c0s,
    const float* __restrict__ xbn, const float* __restrict__ G2x,
    float* __restrict__ H1, float* __restrict__ outp) {
  const int br   = blockIdx.x;
  const int tid  = threadIdx.x;
  const int wave = tid >> 6;
  const int lane = tid & 63;
  const int quad = lane >> 4;
  const int l15  = lane & 15;
  const bool r1 = (l15 & 1) != 0;        // rr bit 0
  const bool r2 = (l15 & 2) != 0;        // rr bit 1
  const bool bh = (l15 & 8) != 0;        // half select
  const bool store_lane = (l15 & 4) == 0;
  const int j = wave * 32 + (l15 >> 3) * 16 + quad * 4 + (l15 & 3);  // h index

  __shared__ __align__(16) _Float16 h_sh[2][128];  // double-buffered h state
  __shared__ float xs[(LAYER == 1) ? 6144 : 64];

  // ---- preload Whh as f16 A-fragments (gate-permuted rows) ----
  half8 afrag[8][4];
#pragma unroll
  for (int mt = 0; mt < 8; ++mt) {
    const int row = (mt >> 1) * 128 + wave * 32 + (mt & 1) * 16 + l15;
#pragma unroll
    for (int kt = 0; kt < 4; ++kt) {
      const float* src = Whh + row * 128 + kt * 32 + quad * 8;
      half8 f;
#pragma unroll
      for (int jj = 0; jj < 8; ++jj) f[jj] = (_Float16)src[jj];
      afrag[mt][kt] = f;
    }
  }

  if (LAYER == 1) {
    for (int i = tid; i < 6144; i += 256) xs[i] = xbn[br * 6144 + i];
  }

  const int s0 = 2 * br + (LAYER - 1);
  float c = c0s[s0 * 128 + j];  // duplicated lanes hold identical state (fine)
  float bi = 0.f, bf = 0.f, bg = 0.f, bo = 0.f;
  float wxi[3] = {0, 0, 0}, wxf[3] = {0, 0, 0}, wxg[3] = {0, 0, 0}, wxo[3] = {0, 0, 0};
  if (LAYER == 1) {
    bi = bih[j] + bhh[j];
    bf = bih[128 + j] + bhh[128 + j];
    bg = bih[256 + j] + bhh[256 + j];
    bo = bih[384 + j] + bhh[384 + j];
#pragma unroll
    for (int d = 0; d < 3; ++d) {
      wxi[d] = Wih[j * 3 + d];
      wxf[d] = Wih[(128 + j) * 3 + d];
      wxg[d] = Wih[(256 + j) * 3 + d];
      wxo[d] = Wih[(384 + j) * 3 + d];
    }
  }
  if (tid < 128) h_sh[0][tid] = (_Float16)h0s[s0 * 128 + tid];

  // LAYER 2: depth-2 register prefetch of G2x gate rows (bias folded in).
  const float* gbase =
      (LAYER == 2) ? (G2x + (size_t)br * 2048 * 512 + j) : (const float*)nullptr;
  float c0g = 0.f, c1g = 0.f, c2g = 0.f, c3g = 0.f;
  float n0g = 0.f, n1g = 0.f, n2g = 0.f, n3g = 0.f;
  if (LAYER == 2) {
    c0g = gbase[0];   c1g = gbase[128]; c2g = gbase[256]; c3g = gbase[384];
    n0g = gbase[512]; n1g = gbase[640]; n2g = gbase[768]; n3g = gbase[896];
  }

  __syncthreads();  // once; full drain is fine here

#pragma unroll 2
  for (int s = 0; s < 2048; ++s) {
    // prefetch step s+2 (hidden under MFMA; no barrier drains it)
    float p0 = 0.f, p1 = 0.f, p2 = 0.f, p3 = 0.f;
    if (LAYER == 2) {
      if (s + 2 < 2048) {
        const float* gp = gbase + (size_t)(s + 2) * 512;
        p0 = gp[0]; p1 = gp[128]; p2 = gp[256]; p3 = gp[384];
      }
    }

    // B fragments: every lane supplies h[k] -> every D column is the matvec
    const _Float16* hcur = h_sh[s & 1];
    half8 bfrag[4];
#pragma unroll
    for (int kt = 0; kt < 4; ++kt)
      bfrag[kt] = *reinterpret_cast<const half8*>(&hcur[kt * 32 + quad * 8]);

    // x / G2x term — independent of h; overlaps the MFMA section
    float xt_i, xt_f, xt_g, xt_o;
    if (LAYER == 1) {
      const float x0 = xs[s * 3], x1 = xs[s * 3 + 1], x2 = xs[s * 3 + 2];
      xt_i = bi + wxi[0] * x0 + wxi[1] * x1 + wxi[2] * x2;
      xt_f = bf + wxf[0] * x0 + wxf[1] * x1 + wxf[2] * x2;
      xt_g = bg + wxg[0] * x0 + wxg[1] * x1 + wxg[2] * x2;
      xt_o = bo + wxo[0] * x0 + wxo[1] * x1 + wxo[2] * x2;
    } else {
      xt_i = c0g; xt_f = c1g; xt_g = c2g; xt_o = c3g;
    }

    float4_t acc[8];
#pragma unroll
    for (int mt = 0; mt < 8; ++mt) acc[mt] = (float4_t){0.f, 0.f, 0.f, 0.f};
#pragma unroll
    for (int kt = 0; kt < 4; ++kt)
#pragma unroll
      for (int mt = 0; mt < 8; ++mt)
        acc[mt] = __builtin_amdgcn_mfma_f32_16x16x32_f16(afrag[mt][kt], bfrag[kt], acc[mt], 0, 0, 0);

    // gate values straight from registers (no LDS round-trip)
    const float gi = gsel(acc[0], acc[1], r1, r2, bh) + xt_i;
    const float gf = gsel(acc[2], acc[3], r1, r2, bh) + xt_f;
    const float gg = gsel(acc[4], acc[5], r1, r2, bh) + xt_g;
    const float go = gsel(acc[6], acc[7], r1, r2, bh) + xt_o;

    const float iv = sigm(gi);
    const float fv = sigm(gf);
    const float gv = tanh_fast(gg);
    const float ov = sigm(go);
    c = fv * c + iv * gv;
    const float hv = ov * tanh_fast(c);

    if (store_lane) {
      h_sh[(s + 1) & 1][j] = (_Float16)hv;
      if (LAYER == 1)
        H1[((size_t)br * 2048 + (size_t)s) * 128 + j] = hv;
      else
        outp[(size_t)br * 262144 + (size_t)s * 128 + j] = hv;
    }
    if (LAYER == 2) {
      c0g = n0g; c1g = n1g; c2g = n2g; c3g = n3g;
      n0g = p0;  n1g = p1;  n2g = p2;  n3g = p3;
    }
    lds_barrier();  // h broadcast; lgkm-only, stores/loads stay in flight
  }
}

// ---------------------------------------------------------------------------
// Workspace layout (floats): xbn@0 (18432) | H1@18432 (786432) |
// stats@804864 (768) | G2x@805632 (3145728)
// ---------------------------------------------------------------------------
extern "C" void kernel_launch(void* const* d_in, const int* in_sizes, int n_in,
                              void* d_out, int out_size, void* d_ws, size_t ws_size,
                              hipStream_t stream) {
  const float* x    = (const float*)d_in[0];
  const float* g1   = (const float*)d_in[1];
  const float* b1   = (const float*)d_in[2];
  const float* Wih1 = (const float*)d_in[3];
  const float* Whh1 = (const float*)d_in[4];
  const float* bih1 = (const float*)d_in[5];
  const float* bhh1 = (const float*)d_in[6];
  const float* g2   = (const float*)d_in[7];
  const float* b2   = (const float*)d_in[8];
  const float* Wih2 = (const float*)d_in[9];
  const float* Whh2 = (const float*)d_in[10];
  const float* bih2 = (const float*)d_in[11];
  const float* bhh2 = (const float*)d_in[12];
  const float* h0s  = (const float*)d_in[13];
  const float* c0s  = (const float*)d_in[14];

  float* ws   = (float*)d_ws;
  float* xbn  = ws;
  float* H1b  = ws + 18432;
  float* st   = ws + 18432 + 786432;
  float* G2xb = st + 768;
  float* outp = (float*)d_out;

  bn1_kernel<<<48, 128, 0, stream>>>(x, g1, b1, xbn);
  lstm_kernel<1><<<3, 256, 0, stream>>>(Whh1, Wih1, bih1, bhh1, h0s, c0s, xbn,
                                        nullptr, H1b, nullptr);
  bn2stats_kernel<<<384, 256, 0, stream>>>(H1b, st);
  g2x_kernel<<<384, 256, 0, stream>>>(H1b, st, g2, b2, Wih2, bih2, bhh2, G2xb);
  lstm_kernel<2><<<3, 256, 0, stream>>>(Whh2, nullptr, bih2, bhh2, h0s, c0s,
                                        nullptr, G2xb, nullptr, outp);
}